// Round 7
// baseline (995.267 us; speedup 1.0000x reference)
//
#include <hip/hip_runtime.h>
#include <math.h>

#define NEG_SLOPE 0.3f
#define BN_EPS 1e-5f

static __device__ __forceinline__ int lower_bound_i(const int* __restrict__ a, int n, int v) {
  int lo = 0, hi = n;
  while (lo < hi) {
    int mid = (lo + hi) >> 1;
    if (a[mid] < v) lo = mid + 1; else hi = mid;
  }
  return lo;
}

// ---------------- init ----------------
__global__ void zero2_kernel(int* __restrict__ a, int* __restrict__ b, int n) {
  int i = blockIdx.x * blockDim.x + threadIdx.x;
  if (i < n) { a[i] = 0; b[i] = 0; }
}

// ---------------- BN/bias fold: scale = g/sqrt(rv+eps); shift = (bias-rm)*scale + b
__global__ void bnprep_kernel(const float* __restrict__ bias, const float* __restrict__ g,
    const float* __restrict__ b, const float* __restrict__ rm, const float* __restrict__ rv,
    float* __restrict__ scale, float* __restrict__ shift) {
  int c = threadIdx.x;  // 128
  float s = g[c] / sqrtf(rv[c] + BN_EPS);
  scale[c] = s;
  shift[c] = (bias[c] - rm[c]) * s + b[c];
}

// ---------------- CSR build ----------------
__global__ void hist_kernel(const int* __restrict__ dst, int ne, int* __restrict__ deg) {
  int i = blockIdx.x * blockDim.x + threadIdx.x;
  int stride = gridDim.x * blockDim.x;
  for (; i < ne; i += stride) atomicAdd(&deg[dst[i]], 1);
}

__global__ __launch_bounds__(1024) void scan_kernel(const int* __restrict__ deg,
    int* __restrict__ offs, int n) {
  __shared__ int part[1024];
  int t = threadIdx.x;
  int chunk = (n + 1023) >> 10;
  int s0 = t * chunk;
  int s1 = min(n, s0 + chunk);
  int sum = 0;
  for (int i = s0; i < s1; ++i) sum += deg[i];
  part[t] = sum;
  __syncthreads();
  for (int off = 1; off < 1024; off <<= 1) {
    int v = (t >= off) ? part[t - off] : 0;
    __syncthreads();
    part[t] += v;
    __syncthreads();
  }
  int run = (t > 0) ? part[t - 1] : 0;
  for (int i = s0; i < s1; ++i) { offs[i] = run; run += deg[i]; }
}

__global__ void scatter_kernel(const int* __restrict__ src, const int* __restrict__ dst,
    int ne, const int* __restrict__ offs, int* __restrict__ cursor,
    int* __restrict__ csr_src) {
  int i = blockIdx.x * blockDim.x + threadIdx.x;
  int stride = gridDim.x * blockDim.x;
  for (; i < ne; i += stride) {
    int d = dst[i];
    int pos = offs[d] + atomicAdd(&cursor[d], 1);
    csr_src[pos] = src[i];
  }
}

// ---------------- GEMM: C[n,128] = A[n,128] @ W[128,128] (fp32), LDS-free ------
// 32-row tiles, block = 256 thr = 8 rowgroups x 32 colgroups; thread owns
// 4 rows x 4 cols (16 acc, ~60 VGPR). No LDS -> ~24+ waves/CU resident
// (R6's 64KB-LDS version was stuck at 8-12 waves/CU, latency-bound ~100us).
// W streamed from L1/L2 (64 KB, hot after first tile); A row loads are
// 32-lane broadcasts (2 distinct 16B addrs per wave instr, L1-served).
__global__ __launch_bounds__(256) void gemm128(const float* __restrict__ A,
    const float* __restrict__ W, float* __restrict__ C, int n) {
  int t = threadIdx.x;
  int cg = t & 31;   // cols 4*cg .. 4*cg+3
  int rg = t >> 5;   // rowgroup 0..7: owns 4 rows
  int ntiles = (n + 31) >> 5;
  for (int tile = blockIdx.x; tile < ntiles; tile += gridDim.x) {
    int r0 = (tile << 5) + rg * 4;
    const float* Ar[4];
#pragma unroll
    for (int r = 0; r < 4; ++r) {
      int gr = min(r0 + r, n - 1);          // clamp for loads; stores guarded
      Ar[r] = A + (size_t)gr * 128;
    }
    float4 acc[4];
#pragma unroll
    for (int r = 0; r < 4; ++r) acc[r] = make_float4(0.f, 0.f, 0.f, 0.f);
#pragma unroll 4
    for (int k = 0; k < 128; k += 4) {
      float4 w0 = *(const float4*)&W[(k + 0) * 128 + cg * 4];
      float4 w1 = *(const float4*)&W[(k + 1) * 128 + cg * 4];
      float4 w2 = *(const float4*)&W[(k + 2) * 128 + cg * 4];
      float4 w3 = *(const float4*)&W[(k + 3) * 128 + cg * 4];
#pragma unroll
      for (int r = 0; r < 4; ++r) {
        float4 av = *(const float4*)(Ar[r] + k);
        acc[r].x += av.x * w0.x + av.y * w1.x + av.z * w2.x + av.w * w3.x;
        acc[r].y += av.x * w0.y + av.y * w1.y + av.z * w2.y + av.w * w3.y;
        acc[r].z += av.x * w0.z + av.y * w1.z + av.z * w2.z + av.w * w3.z;
        acc[r].w += av.x * w0.w + av.y * w1.w + av.z * w2.w + av.w * w3.w;
      }
    }
#pragma unroll
    for (int r = 0; r < 4; ++r) {
      int gr = r0 + r;
      if (gr < n) *(float4*)&C[(size_t)gr * 128 + cg * 4] = acc[r];
    }
  }
}

// ---------------- gate: gate[n] = tanh(h2 @ Wg1 + bg1) . Wg2 -------------------
// Same LDS-free skeleton; epilogue: tanh + dot(Wg2) + 32-lane reduce.
__global__ __launch_bounds__(256) void gate_kernel(const float* __restrict__ A,
    const float* __restrict__ Wg1, const float* __restrict__ bg1,
    const float* __restrict__ Wg2, float* __restrict__ gate, int n) {
  int t = threadIdx.x;
  int cg = t & 31;
  int rg = t >> 5;
  float4 bg4 = *(const float4*)&bg1[cg * 4];
  float4 wg4 = *(const float4*)&Wg2[cg * 4];
  int ntiles = (n + 31) >> 5;
  for (int tile = blockIdx.x; tile < ntiles; tile += gridDim.x) {
    int r0 = (tile << 5) + rg * 4;
    const float* Ar[4];
#pragma unroll
    for (int r = 0; r < 4; ++r) {
      int gr = min(r0 + r, n - 1);
      Ar[r] = A + (size_t)gr * 128;
    }
    float4 acc[4];
#pragma unroll
    for (int r = 0; r < 4; ++r) acc[r] = make_float4(0.f, 0.f, 0.f, 0.f);
#pragma unroll 4
    for (int k = 0; k < 128; k += 4) {
      float4 w0 = *(const float4*)&Wg1[(k + 0) * 128 + cg * 4];
      float4 w1 = *(const float4*)&Wg1[(k + 1) * 128 + cg * 4];
      float4 w2 = *(const float4*)&Wg1[(k + 2) * 128 + cg * 4];
      float4 w3 = *(const float4*)&Wg1[(k + 3) * 128 + cg * 4];
#pragma unroll
      for (int r = 0; r < 4; ++r) {
        float4 av = *(const float4*)(Ar[r] + k);
        acc[r].x += av.x * w0.x + av.y * w1.x + av.z * w2.x + av.w * w3.x;
        acc[r].y += av.x * w0.y + av.y * w1.y + av.z * w2.y + av.w * w3.y;
        acc[r].z += av.x * w0.z + av.y * w1.z + av.z * w2.z + av.w * w3.z;
        acc[r].w += av.x * w0.w + av.y * w1.w + av.z * w2.w + av.w * w3.w;
      }
    }
#pragma unroll
    for (int r = 0; r < 4; ++r) {
      float v = tanhf(acc[r].x + bg4.x) * wg4.x
              + tanhf(acc[r].y + bg4.y) * wg4.y
              + tanhf(acc[r].z + bg4.z) * wg4.z
              + tanhf(acc[r].w + bg4.w) * wg4.w;
      v += __shfl_xor(v, 1);
      v += __shfl_xor(v, 2);
      v += __shfl_xor(v, 4);
      v += __shfl_xor(v, 8);
      v += __shfl_xor(v, 16);
      int gr = r0 + r;
      if (cg == 0 && gr < n) gate[gr] = v;
    }
  }
}

// ---------------- GATv2 layer FUSED: one wave per node, 8 edges x 8 chunks -----
// Block = 256 thr (4 waves); wave w handles node blockIdx*4+w (non-persistent:
// R5/R6's per-wave node loop serialized epilogue->next-node, 138 vs 122 us).
// Lane = (edge-slot es = l>>3, chunk c = l&7); lane owns 16 channels c*16..+15.
// Layer 1 (REDUCE=false): chunk == head, score completes in-lane.
// Layer 2 (REDUCE=true): score = 128-dot, reduce over the 8 chunk lanes.
// No max-subtraction (scores O(1), softmax shift-invariant, exp safe).
// NOTE: no min-waves in launch_bounds (R4: forcing 6/EU spilled -> 4x slower).
template<bool REDUCE>
__global__ __launch_bounds__(256) void gat_fused(
    const float* __restrict__ xl, const float* __restrict__ xr,
    const int* __restrict__ csr_src, const int* __restrict__ offs,
    const int* __restrict__ deg, const float* __restrict__ att,
    const float* __restrict__ bnscale, const float* __restrict__ bnshift,
    float* __restrict__ out, int n_nodes) {
  int l = threadIdx.x & 63;
  int n = blockIdx.x * 4 + (threadIdx.x >> 6);
  if (n >= n_nodes) return;
  int c = l & 7;
  int es = l >> 3;
  int co = c * 16;

  float4 at4[4], xr4[4];
  {
    const float4* atp = (const float4*)(att + co);
    const float4* xrp = (const float4*)(xr + (size_t)n * 128 + co);
#pragma unroll
    for (int j = 0; j < 4; ++j) { at4[j] = atp[j]; xr4[j] = xrp[j]; }
  }
  int base = offs[n], d = deg[n];
  float acc[16];
#pragma unroll
  for (int j = 0; j < 16; ++j) acc[j] = 0.f;
  float ssum = 0.f;

  const int* cp = csr_src + base;
  int iters = (d + 7) >> 3;

  auto loadgrp = [&](int eidx, float4* v) -> bool {
    bool valid = eidx < d;
    int ecl = valid ? eidx : (d - 1);
    int sidx = cp[ecl];
    const float4* xp = (const float4*)(xl + (size_t)sidx * 128 + co);
#pragma unroll
    for (int j = 0; j < 4; ++j) v[j] = xp[j];
    return valid;
  };
  auto compute = [&](const float4* v, bool valid) {
    float p = 0.f;
#pragma unroll
    for (int j = 0; j < 4; ++j) {
      float t0 = v[j].x + xr4[j].x;
      float t1 = v[j].y + xr4[j].y;
      float t2 = v[j].z + xr4[j].z;
      float t3 = v[j].w + xr4[j].w;
      p += at4[j].x * (fmaxf(t0, 0.f) + NEG_SLOPE * fminf(t0, 0.f));
      p += at4[j].y * (fmaxf(t1, 0.f) + NEG_SLOPE * fminf(t1, 0.f));
      p += at4[j].z * (fmaxf(t2, 0.f) + NEG_SLOPE * fminf(t2, 0.f));
      p += at4[j].w * (fmaxf(t3, 0.f) + NEG_SLOPE * fminf(t3, 0.f));
    }
    if (REDUCE) {
      p += __shfl_xor(p, 1);
      p += __shfl_xor(p, 2);
      p += __shfl_xor(p, 4);
    }
    float ex = valid ? __expf(p) : 0.f;
    ssum += ex;
#pragma unroll
    for (int j = 0; j < 4; ++j) {
      acc[4 * j + 0] += ex * v[j].x;
      acc[4 * j + 1] += ex * v[j].y;
      acc[4 * j + 2] += ex * v[j].z;
      acc[4 * j + 3] += ex * v[j].w;
    }
  };

  int i = 0;
  for (; i + 2 <= iters; i += 2) {
    float4 v0[4], v1[4];
    bool a = loadgrp((i << 3) + es, v0);
    bool b = loadgrp(((i + 1) << 3) + es, v1);
    compute(v0, a);
    compute(v1, b);
  }
  if (i < iters) {
    float4 v0[4];
    bool a = loadgrp((i << 3) + es, v0);
    compute(v0, a);
  }

  // reduce across the 8 edge slots (once per node)
#pragma unroll
  for (int st = 8; st <= 32; st <<= 1) {
    ssum += __shfl_xor(ssum, st);
#pragma unroll
    for (int j = 0; j < 16; ++j) acc[j] += __shfl_xor(acc[j], st);
  }

  if (es == 0) {
    float inv = 1.f / (ssum + 1e-16f);
    const float4* scp = (const float4*)(bnscale + co);
    const float4* shp = (const float4*)(bnshift + co);
    float4* op = (float4*)(out + (size_t)n * 128 + co);
#pragma unroll
    for (int j = 0; j < 4; ++j) {
      float4 sc = scp[j], sh = shp[j];
      float4 o;
      o.x = fmaxf(acc[4 * j + 0] * inv * sc.x + sh.x, 0.f);
      o.y = fmaxf(acc[4 * j + 1] * inv * sc.y + sh.y, 0.f);
      o.z = fmaxf(acc[4 * j + 2] * inv * sc.z + sh.z, 0.f);
      o.w = fmaxf(acc[4 * j + 3] * inv * sc.w + sh.w, 0.f);
      op[j] = o;
    }
  }
}

// ---------------- attentional pooling per graph ----------------
__global__ __launch_bounds__(128) void pool_kernel(const float* __restrict__ gate,
    const float* __restrict__ h2, const int* __restrict__ batch, int n_nodes,
    float* __restrict__ pooled, int n_graphs) {
  int g = blockIdx.x;
  if (g >= n_graphs) return;
  int t = threadIdx.x;
  int start = lower_bound_i(batch, n_nodes, g);
  int end = lower_bound_i(batch, n_nodes, g + 1);
  __shared__ float red[128];
  float m = -__builtin_inff();
  for (int i = start + t; i < end; i += 128) m = fmaxf(m, gate[i]);
  red[t] = m;
  __syncthreads();
  for (int off = 64; off >= 1; off >>= 1) {
    if (t < off) red[t] = fmaxf(red[t], red[t + off]);
    __syncthreads();
  }
  m = red[0];
  float s = 0.f, acc = 0.f;
  for (int i = start; i < end; ++i) {
    float ex = __expf(gate[i] - m);
    s += ex;
    acc += ex * h2[(size_t)i * 128 + t];
  }
  pooled[(size_t)g * 128 + t] = acc / (s + 1e-16f);
}

// ---------------- fc head: out = relu(pooled @ Wf1 + bf1) @ Wf2 + bf2 ----------
__global__ __launch_bounds__(128) void fc_kernel(const float* __restrict__ pooled,
    const float* __restrict__ Wf1, const float* __restrict__ bf1,
    const float* __restrict__ Wf2, const float* __restrict__ bf2,
    float* __restrict__ out, int n_graphs) {
  int g = blockIdx.x;
  if (g >= n_graphs) return;
  int t = threadIdx.x;
  __shared__ float pl[128];
  __shared__ float red[128];
  pl[t] = pooled[(size_t)g * 128 + t];
  __syncthreads();
  float v = 0.f;
  if (t < 100) {
    float acc = bf1[t];
    for (int k = 0; k < 128; ++k) acc += pl[k] * Wf1[k * 100 + t];
    v = fmaxf(acc, 0.f) * Wf2[t];
  }
  red[t] = v;
  __syncthreads();
  for (int off = 64; off >= 1; off >>= 1) {
    if (t < off) red[t] += red[t + off];
    __syncthreads();
  }
  if (t == 0) out[g] = red[0] + bf2[0];
}

extern "C" void kernel_launch(void* const* d_in, const int* in_sizes, int n_in,
                              void* d_out, int out_size, void* d_ws, size_t ws_size,
                              hipStream_t stream) {
  const float* x     = (const float*)d_in[0];
  const int*   ei    = (const int*)d_in[1];
  const int*   batch = (const int*)d_in[2];
  const float* Wl1   = (const float*)d_in[3];
  const float* Wr1   = (const float*)d_in[4];
  const float* att1  = (const float*)d_in[5];
  const float* b1    = (const float*)d_in[6];
  const float* Wl2   = (const float*)d_in[7];
  const float* Wr2   = (const float*)d_in[8];
  const float* att2  = (const float*)d_in[9];
  const float* b2    = (const float*)d_in[10];
  const float* bn_g  = (const float*)d_in[11];
  const float* bn_b  = (const float*)d_in[12];
  const float* bn_rm = (const float*)d_in[13];
  const float* bn_rv = (const float*)d_in[14];
  const float* Wg1   = (const float*)d_in[15];
  const float* bg1   = (const float*)d_in[16];
  const float* Wg2   = (const float*)d_in[17];
  const float* Wf1   = (const float*)d_in[18];
  const float* bf1   = (const float*)d_in[19];
  const float* Wf2   = (const float*)d_in[20];
  const float* bf2   = (const float*)d_in[21];

  const int N  = in_sizes[0] / 128;
  const int E  = in_sizes[1] / 2;
  const int NG = out_size;
  const int* src = ei;
  const int* dst = ei + E;

  // ---- workspace arena (256B-aligned) ----
  char* p = (char*)d_ws;
  auto alloc = [&](size_t bytes) -> void* {
    void* r = (void*)p;
    p += (bytes + 255) & ~(size_t)255;
    return r;
  };
  float* bufA    = (float*)alloc((size_t)N * 128 * 4);  // xl1, later xl2
  float* bufB    = (float*)alloc((size_t)N * 128 * 4);  // xr1, later xr2
  float* h1      = (float*)alloc((size_t)N * 128 * 4);  // h1, later reused as h2
  int*   deg     = (int*)alloc((size_t)N * 4);
  int*   cursor  = (int*)alloc((size_t)N * 4);
  int*   offs    = (int*)alloc((size_t)N * 4);
  int*   csr_src = (int*)alloc((size_t)E * 4);
  float* gate    = (float*)alloc((size_t)N * 4);
  float* pooled  = (float*)alloc((size_t)NG * 128 * 4);
  float* bns1    = (float*)alloc(128 * 4);
  float* bnh1    = (float*)alloc(128 * 4);
  float* bns2    = (float*)alloc(128 * 4);
  float* bnh2    = (float*)alloc(128 * 4);
  float* h2      = h1;  // h1 dead after layer-2 GEMMs; safe alias (in-order stream)

  const int gemm_grid = (N + 31) >> 5;       // 32-row tiles, one per block
  const int gat_grid  = (N + 3) >> 2;        // 4 nodes per 256-thr block

  // ---- CSR build + BN prep ----
  zero2_kernel<<<(N + 255) / 256, 256, 0, stream>>>(deg, cursor, N);
  hist_kernel<<<1024, 256, 0, stream>>>(dst, E, deg);
  scan_kernel<<<1, 1024, 0, stream>>>(deg, offs, N);
  scatter_kernel<<<1024, 256, 0, stream>>>(src, dst, E, offs, cursor, csr_src);
  bnprep_kernel<<<1, 128, 0, stream>>>(b1, bn_g, bn_b, bn_rm, bn_rv, bns1, bnh1);
  bnprep_kernel<<<1, 128, 0, stream>>>(b2, bn_g, bn_b, bn_rm, bn_rv, bns2, bnh2);

  // ---- layer 1 ----
  gemm128<<<gemm_grid, 256, 0, stream>>>(x, Wl1, bufA, N);
  gemm128<<<gemm_grid, 256, 0, stream>>>(x, Wr1, bufB, N);
  gat_fused<false><<<gat_grid, 256, 0, stream>>>(bufA, bufB, csr_src, offs, deg, att1,
                                                 bns1, bnh1, h1, N);

  // ---- layer 2 ----
  gemm128<<<gemm_grid, 256, 0, stream>>>(h1, Wl2, bufA, N);
  gemm128<<<gemm_grid, 256, 0, stream>>>(h1, Wr2, bufB, N);
  gat_fused<true><<<gat_grid, 256, 0, stream>>>(bufA, bufB, csr_src, offs, deg, att2,
                                                bns2, bnh2, h2, N);

  // ---- pooling + head ----
  gate_kernel<<<gemm_grid, 256, 0, stream>>>(h2, Wg1, bg1, Wg2, gate, N);
  pool_kernel<<<NG, 128, 0, stream>>>(gate, h2, batch, N, pooled, NG);
  fc_kernel<<<NG, 128, 0, stream>>>(pooled, Wf1, bf1, Wf2, bf2, (float*)d_out, NG);
}

// Round 8
// 835.379 us; speedup vs baseline: 1.1914x; 1.1914x over previous
//
#include <hip/hip_runtime.h>
#include <math.h>

#define NEG_SLOPE 0.3f
#define BN_EPS 1e-5f

static __device__ __forceinline__ int lower_bound_i(const int* __restrict__ a, int n, int v) {
  int lo = 0, hi = n;
  while (lo < hi) {
    int mid = (lo + hi) >> 1;
    if (a[mid] < v) lo = mid + 1; else hi = mid;
  }
  return lo;
}

// ---------------- init ----------------
__global__ void zero2_kernel(int* __restrict__ a, int* __restrict__ b, int n) {
  int i = blockIdx.x * blockDim.x + threadIdx.x;
  if (i < n) { a[i] = 0; b[i] = 0; }
}

// ---------------- BN/bias fold for BOTH layers in one launch -------------------
// scale = g/sqrt(rv+eps); shift = (bias-rm)*scale + b. t<128 -> layer1, else layer2.
__global__ void bnprep2_kernel(const float* __restrict__ b1, const float* __restrict__ b2,
    const float* __restrict__ g, const float* __restrict__ bb,
    const float* __restrict__ rm, const float* __restrict__ rv,
    float* __restrict__ s1, float* __restrict__ h1, float* __restrict__ s2,
    float* __restrict__ h2) {
  int t = threadIdx.x;  // 256
  int c = t & 127;
  float s = g[c] / sqrtf(rv[c] + BN_EPS);
  const float* bias = (t < 128) ? b1 : b2;
  float* so = (t < 128) ? s1 : s2;
  float* ho = (t < 128) ? h1 : h2;
  so[c] = s;
  ho[c] = (bias[c] - rm[c]) * s + bb[c];
}

// ---------------- CSR build ----------------
__global__ void hist_kernel(const int* __restrict__ dst, int ne, int* __restrict__ deg) {
  int i = blockIdx.x * blockDim.x + threadIdx.x;
  int stride = gridDim.x * blockDim.x;
  for (; i < ne; i += stride) atomicAdd(&deg[dst[i]], 1);
}

__global__ __launch_bounds__(1024) void scan_kernel(const int* __restrict__ deg,
    int* __restrict__ offs, int n) {
  __shared__ int part[1024];
  int t = threadIdx.x;
  int chunk = (n + 1023) >> 10;
  int s0 = t * chunk;
  int s1 = min(n, s0 + chunk);
  int sum = 0;
  for (int i = s0; i < s1; ++i) sum += deg[i];
  part[t] = sum;
  __syncthreads();
  for (int off = 1; off < 1024; off <<= 1) {
    int v = (t >= off) ? part[t - off] : 0;
    __syncthreads();
    part[t] += v;
    __syncthreads();
  }
  int run = (t > 0) ? part[t - 1] : 0;
  for (int i = s0; i < s1; ++i) { offs[i] = run; run += deg[i]; }
}

// csr_src stored as uint16 (node ids < 65536): halves random-scatter payload.
__global__ void scatter_kernel(const int* __restrict__ src, const int* __restrict__ dst,
    int ne, const int* __restrict__ offs, int* __restrict__ cursor,
    unsigned short* __restrict__ csr_src) {
  int i = blockIdx.x * blockDim.x + threadIdx.x;
  int stride = gridDim.x * blockDim.x;
  for (; i < ne; i += stride) {
    int d = dst[i];
    int pos = offs[d] + atomicAdd(&cursor[d], 1);
    csr_src[pos] = (unsigned short)src[i];
  }
}

// ---------------- GEMM: C[n,128] = A[n,128] @ W[128,128] (fp32) ----------------
// R4-proven config: W fully staged in LDS (64 KB). Block = 512 thr (8 waves),
// 128-row tiles, thread = 8 rows x 4 cols; 2 blocks/CU -> 16 waves/CU.
// (R7's LDS-free variant regressed: W can't fit L1, every wave re-streams L2.)
__global__ __launch_bounds__(512) void gemm128(const float* __restrict__ A,
    const float* __restrict__ W, float* __restrict__ C, int n) {
  __shared__ float Wl[128 * 128];  // 64 KB
  int t = threadIdx.x;
  for (int i = t; i < 4096; i += 512)
    ((float4*)Wl)[i] = ((const float4*)W)[i];
  __syncthreads();
  int cg = t & 31;   // colgroup: owns cols 4*cg .. 4*cg+3
  int rg = t >> 5;   // rowgroup 0..15: owns 8 rows
  int ntiles = (n + 127) >> 7;
  for (int tile = blockIdx.x; tile < ntiles; tile += gridDim.x) {
    int r0 = (tile << 7) + rg * 8;
    const float* Ar[8];
#pragma unroll
    for (int r = 0; r < 8; ++r) {
      int gr = min(r0 + r, n - 1);          // clamp for loads; stores guarded
      Ar[r] = A + (size_t)gr * 128;
    }
    float4 acc[8];
#pragma unroll
    for (int r = 0; r < 8; ++r) acc[r] = make_float4(0.f, 0.f, 0.f, 0.f);
#pragma unroll 4
    for (int k = 0; k < 128; k += 4) {
      float4 w0 = *(const float4*)&Wl[(k + 0) * 128 + cg * 4];
      float4 w1 = *(const float4*)&Wl[(k + 1) * 128 + cg * 4];
      float4 w2 = *(const float4*)&Wl[(k + 2) * 128 + cg * 4];
      float4 w3 = *(const float4*)&Wl[(k + 3) * 128 + cg * 4];
#pragma unroll
      for (int r = 0; r < 8; ++r) {
        float4 av = *(const float4*)(Ar[r] + k);
        acc[r].x += av.x * w0.x + av.y * w1.x + av.z * w2.x + av.w * w3.x;
        acc[r].y += av.x * w0.y + av.y * w1.y + av.z * w2.y + av.w * w3.y;
        acc[r].z += av.x * w0.z + av.y * w1.z + av.z * w2.z + av.w * w3.z;
        acc[r].w += av.x * w0.w + av.y * w1.w + av.z * w2.w + av.w * w3.w;
      }
    }
#pragma unroll
    for (int r = 0; r < 8; ++r) {
      int gr = r0 + r;
      if (gr < n) *(float4*)&C[(size_t)gr * 128 + cg * 4] = acc[r];
    }
  }
}

// ---------------- gate: gate[n] = tanh(h2 @ Wg1 + bg1) . Wg2 -------------------
__global__ __launch_bounds__(512) void gate_kernel(const float* __restrict__ A,
    const float* __restrict__ Wg1, const float* __restrict__ bg1,
    const float* __restrict__ Wg2, float* __restrict__ gate, int n) {
  __shared__ float Wl[128 * 128];  // 64 KB
  int t = threadIdx.x;
  for (int i = t; i < 4096; i += 512)
    ((float4*)Wl)[i] = ((const float4*)Wg1)[i];
  __syncthreads();
  int cg = t & 31;
  int rg = t >> 5;
  float4 bg4 = *(const float4*)&bg1[cg * 4];
  float4 wg4 = *(const float4*)&Wg2[cg * 4];
  int ntiles = (n + 127) >> 7;
  for (int tile = blockIdx.x; tile < ntiles; tile += gridDim.x) {
    int r0 = (tile << 7) + rg * 8;
    const float* Ar[8];
#pragma unroll
    for (int r = 0; r < 8; ++r) {
      int gr = min(r0 + r, n - 1);
      Ar[r] = A + (size_t)gr * 128;
    }
    float4 acc[8];
#pragma unroll
    for (int r = 0; r < 8; ++r) acc[r] = make_float4(0.f, 0.f, 0.f, 0.f);
#pragma unroll 4
    for (int k = 0; k < 128; k += 4) {
      float4 w0 = *(const float4*)&Wl[(k + 0) * 128 + cg * 4];
      float4 w1 = *(const float4*)&Wl[(k + 1) * 128 + cg * 4];
      float4 w2 = *(const float4*)&Wl[(k + 2) * 128 + cg * 4];
      float4 w3 = *(const float4*)&Wl[(k + 3) * 128 + cg * 4];
#pragma unroll
      for (int r = 0; r < 8; ++r) {
        float4 av = *(const float4*)(Ar[r] + k);
        acc[r].x += av.x * w0.x + av.y * w1.x + av.z * w2.x + av.w * w3.x;
        acc[r].y += av.x * w0.y + av.y * w1.y + av.z * w2.y + av.w * w3.y;
        acc[r].z += av.x * w0.z + av.y * w1.z + av.z * w2.z + av.w * w3.z;
        acc[r].w += av.x * w0.w + av.y * w1.w + av.z * w2.w + av.w * w3.w;
      }
    }
#pragma unroll
    for (int r = 0; r < 8; ++r) {
      float v = tanhf(acc[r].x + bg4.x) * wg4.x
              + tanhf(acc[r].y + bg4.y) * wg4.y
              + tanhf(acc[r].z + bg4.z) * wg4.z
              + tanhf(acc[r].w + bg4.w) * wg4.w;
      v += __shfl_xor(v, 1);
      v += __shfl_xor(v, 2);
      v += __shfl_xor(v, 4);
      v += __shfl_xor(v, 8);
      v += __shfl_xor(v, 16);
      int gr = r0 + r;
      if (cg == 0 && gr < n) gate[gr] = v;
    }
  }
}

// ---------------- GATv2 layer FUSED: one wave per node (R4-proven shape) -------
// block=64, grid=N: empirically fastest of 3 dispatch shapes tried (122 vs
// 138 persistent vs 148 4-wave-blocks). Lane = (edge-slot es = l>>3, chunk
// c = l&7); lane owns 16 channels. Edge loop unrolled x4 (avg degree 32 ->
// exactly one unrolled iter; 16 float4 gathers in flight vs ~600cyc LLC lat).
// No max-subtraction (scores O(1), softmax shift-invariant, exp safe).
template<bool REDUCE>
__global__ __launch_bounds__(64) void gat_fused(
    const float* __restrict__ xl, const float* __restrict__ xr,
    const unsigned short* __restrict__ csr_src, const int* __restrict__ offs,
    const int* __restrict__ deg, const float* __restrict__ att,
    const float* __restrict__ bnscale, const float* __restrict__ bnshift,
    float* __restrict__ out, int n_nodes) {
  int n = blockIdx.x;
  if (n >= n_nodes) return;
  int l = threadIdx.x;
  int c = l & 7;
  int es = l >> 3;
  int co = c * 16;

  float4 at4[4], xr4[4];
  {
    const float4* atp = (const float4*)(att + co);
    const float4* xrp = (const float4*)(xr + (size_t)n * 128 + co);
#pragma unroll
    for (int j = 0; j < 4; ++j) { at4[j] = atp[j]; xr4[j] = xrp[j]; }
  }
  int base = offs[n], d = deg[n];
  float acc[16];
#pragma unroll
  for (int j = 0; j < 16; ++j) acc[j] = 0.f;
  float ssum = 0.f;

  const unsigned short* cp = csr_src + base;
  int iters = (d + 7) >> 3;

  auto loadgrp = [&](int eidx, float4* v) -> bool {
    bool valid = eidx < d;
    int ecl = valid ? eidx : (d - 1);
    int sidx = (int)cp[ecl];
    const float4* xp = (const float4*)(xl + (size_t)sidx * 128 + co);
#pragma unroll
    for (int j = 0; j < 4; ++j) v[j] = xp[j];
    return valid;
  };
  auto compute = [&](const float4* v, bool valid) {
    float p = 0.f;
#pragma unroll
    for (int j = 0; j < 4; ++j) {
      float t0 = v[j].x + xr4[j].x;
      float t1 = v[j].y + xr4[j].y;
      float t2 = v[j].z + xr4[j].z;
      float t3 = v[j].w + xr4[j].w;
      p += at4[j].x * (fmaxf(t0, 0.f) + NEG_SLOPE * fminf(t0, 0.f));
      p += at4[j].y * (fmaxf(t1, 0.f) + NEG_SLOPE * fminf(t1, 0.f));
      p += at4[j].z * (fmaxf(t2, 0.f) + NEG_SLOPE * fminf(t2, 0.f));
      p += at4[j].w * (fmaxf(t3, 0.f) + NEG_SLOPE * fminf(t3, 0.f));
    }
    if (REDUCE) {
      p += __shfl_xor(p, 1);
      p += __shfl_xor(p, 2);
      p += __shfl_xor(p, 4);
    }
    float ex = valid ? __expf(p) : 0.f;
    ssum += ex;
#pragma unroll
    for (int j = 0; j < 4; ++j) {
      acc[4 * j + 0] += ex * v[j].x;
      acc[4 * j + 1] += ex * v[j].y;
      acc[4 * j + 2] += ex * v[j].z;
      acc[4 * j + 3] += ex * v[j].w;
    }
  };

  int i = 0;
  for (; i + 4 <= iters; i += 4) {
    float4 v0[4], v1[4], v2[4], v3[4];
    bool a0 = loadgrp(((i + 0) << 3) + es, v0);
    bool a1 = loadgrp(((i + 1) << 3) + es, v1);
    bool a2 = loadgrp(((i + 2) << 3) + es, v2);
    bool a3 = loadgrp(((i + 3) << 3) + es, v3);
    compute(v0, a0);
    compute(v1, a1);
    compute(v2, a2);
    compute(v3, a3);
  }
  for (; i < iters; ++i) {
    float4 v0[4];
    bool a = loadgrp((i << 3) + es, v0);
    compute(v0, a);
  }

  // reduce across the 8 edge slots (once per node)
#pragma unroll
  for (int st = 8; st <= 32; st <<= 1) {
    ssum += __shfl_xor(ssum, st);
#pragma unroll
    for (int j = 0; j < 16; ++j) acc[j] += __shfl_xor(acc[j], st);
  }

  if (es == 0) {
    float inv = 1.f / (ssum + 1e-16f);
    const float4* scp = (const float4*)(bnscale + co);
    const float4* shp = (const float4*)(bnshift + co);
    float4* op = (float4*)(out + (size_t)n * 128 + co);
#pragma unroll
    for (int j = 0; j < 4; ++j) {
      float4 sc = scp[j], sh = shp[j];
      float4 o;
      o.x = fmaxf(acc[4 * j + 0] * inv * sc.x + sh.x, 0.f);
      o.y = fmaxf(acc[4 * j + 1] * inv * sc.y + sh.y, 0.f);
      o.z = fmaxf(acc[4 * j + 2] * inv * sc.z + sh.z, 0.f);
      o.w = fmaxf(acc[4 * j + 3] * inv * sc.w + sh.w, 0.f);
      op[j] = o;
    }
  }
}

// ---------------- pooling + fc head fused (one block per graph) ----------------
__global__ __launch_bounds__(128) void poolfc_kernel(const float* __restrict__ gate,
    const float* __restrict__ h2, const int* __restrict__ batch, int n_nodes,
    const float* __restrict__ Wf1, const float* __restrict__ bf1,
    const float* __restrict__ Wf2, const float* __restrict__ bf2,
    float* __restrict__ out, int n_graphs) {
  int g = blockIdx.x;
  if (g >= n_graphs) return;
  int t = threadIdx.x;
  int start = lower_bound_i(batch, n_nodes, g);
  int end = lower_bound_i(batch, n_nodes, g + 1);
  __shared__ float red[128];
  __shared__ float pl[128];
  float m = -__builtin_inff();
  for (int i = start + t; i < end; i += 128) m = fmaxf(m, gate[i]);
  red[t] = m;
  __syncthreads();
  for (int off = 64; off >= 1; off >>= 1) {
    if (t < off) red[t] = fmaxf(red[t], red[t + off]);
    __syncthreads();
  }
  m = red[0];
  __syncthreads();
  float s = 0.f, acc = 0.f;
  for (int i = start; i < end; ++i) {
    float ex = __expf(gate[i] - m);
    s += ex;
    acc += ex * h2[(size_t)i * 128 + t];
  }
  pl[t] = acc / (s + 1e-16f);
  __syncthreads();
  float v = 0.f;
  if (t < 100) {
    float a = bf1[t];
    for (int k = 0; k < 128; ++k) a += pl[k] * Wf1[k * 100 + t];
    v = fmaxf(a, 0.f) * Wf2[t];
  }
  red[t] = v;
  __syncthreads();
  for (int off = 64; off >= 1; off >>= 1) {
    if (t < off) red[t] += red[t + off];
    __syncthreads();
  }
  if (t == 0) out[g] = red[0] + bf2[0];
}

extern "C" void kernel_launch(void* const* d_in, const int* in_sizes, int n_in,
                              void* d_out, int out_size, void* d_ws, size_t ws_size,
                              hipStream_t stream) {
  const float* x     = (const float*)d_in[0];
  const int*   ei    = (const int*)d_in[1];
  const int*   batch = (const int*)d_in[2];
  const float* Wl1   = (const float*)d_in[3];
  const float* Wr1   = (const float*)d_in[4];
  const float* att1  = (const float*)d_in[5];
  const float* b1    = (const float*)d_in[6];
  const float* Wl2   = (const float*)d_in[7];
  const float* Wr2   = (const float*)d_in[8];
  const float* att2  = (const float*)d_in[9];
  const float* b2    = (const float*)d_in[10];
  const float* bn_g  = (const float*)d_in[11];
  const float* bn_b  = (const float*)d_in[12];
  const float* bn_rm = (const float*)d_in[13];
  const float* bn_rv = (const float*)d_in[14];
  const float* Wg1   = (const float*)d_in[15];
  const float* bg1   = (const float*)d_in[16];
  const float* Wg2   = (const float*)d_in[17];
  const float* Wf1   = (const float*)d_in[18];
  const float* bf1   = (const float*)d_in[19];
  const float* Wf2   = (const float*)d_in[20];
  const float* bf2   = (const float*)d_in[21];

  const int N  = in_sizes[0] / 128;
  const int E  = in_sizes[1] / 2;
  const int NG = out_size;
  const int* src = ei;
  const int* dst = ei + E;

  // ---- workspace arena (256B-aligned) ----
  char* p = (char*)d_ws;
  auto alloc = [&](size_t bytes) -> void* {
    void* r = (void*)p;
    p += (bytes + 255) & ~(size_t)255;
    return r;
  };
  float* bufA    = (float*)alloc((size_t)N * 128 * 4);  // xl1, later xl2
  float* bufB    = (float*)alloc((size_t)N * 128 * 4);  // xr1, later xr2
  float* h1      = (float*)alloc((size_t)N * 128 * 4);  // h1, later reused as h2
  int*   deg     = (int*)alloc((size_t)N * 4);
  int*   cursor  = (int*)alloc((size_t)N * 4);
  int*   offs    = (int*)alloc((size_t)N * 4);
  unsigned short* csr_src = (unsigned short*)alloc((size_t)E * 2);
  float* gate    = (float*)alloc((size_t)N * 4);
  float* bns1    = (float*)alloc(128 * 4);
  float* bnh1    = (float*)alloc(128 * 4);
  float* bns2    = (float*)alloc(128 * 4);
  float* bnh2    = (float*)alloc(128 * 4);
  float* h2      = h1;  // h1 dead after layer-2 GEMMs; safe alias (in-order stream)

  const int gemm_grid = (N + 127) >> 7;

  // ---- CSR build + BN prep ----
  zero2_kernel<<<(N + 255) / 256, 256, 0, stream>>>(deg, cursor, N);
  hist_kernel<<<1024, 256, 0, stream>>>(dst, E, deg);
  scan_kernel<<<1, 1024, 0, stream>>>(deg, offs, N);
  scatter_kernel<<<1024, 256, 0, stream>>>(src, dst, E, offs, cursor, csr_src);
  bnprep2_kernel<<<1, 256, 0, stream>>>(b1, b2, bn_g, bn_b, bn_rm, bn_rv,
                                        bns1, bnh1, bns2, bnh2);

  // ---- layer 1 ----
  gemm128<<<gemm_grid, 512, 0, stream>>>(x, Wl1, bufA, N);
  gemm128<<<gemm_grid, 512, 0, stream>>>(x, Wr1, bufB, N);
  gat_fused<false><<<N, 64, 0, stream>>>(bufA, bufB, csr_src, offs, deg, att1,
                                         bns1, bnh1, h1, N);

  // ---- layer 2 ----
  gemm128<<<gemm_grid, 512, 0, stream>>>(h1, Wl2, bufA, N);
  gemm128<<<gemm_grid, 512, 0, stream>>>(h1, Wr2, bufB, N);
  gat_fused<true><<<N, 64, 0, stream>>>(bufA, bufB, csr_src, offs, deg, att2,
                                        bns2, bnh2, h2, N);

  // ---- pooling + head ----
  gate_kernel<<<gemm_grid, 512, 0, stream>>>(h2, Wg1, bg1, Wg2, gate, N);
  poolfc_kernel<<<NG, 128, 0, stream>>>(gate, h2, batch, N, Wf1, bf1, Wf2, bf2,
                                        (float*)d_out, NG);
}

// Round 9
// 781.771 us; speedup vs baseline: 1.2731x; 1.0686x over previous
//
#include <hip/hip_runtime.h>
#include <math.h>

#define NEG_SLOPE 0.3f
#define BN_EPS 1e-5f

static __device__ __forceinline__ int lower_bound_i(const int* __restrict__ a, int n, int v) {
  int lo = 0, hi = n;
  while (lo < hi) {
    int mid = (lo + hi) >> 1;
    if (a[mid] < v) lo = mid + 1; else hi = mid;
  }
  return lo;
}

// ---------------- init ----------------
__global__ void zero2_kernel(int* __restrict__ a, int* __restrict__ b, int n) {
  int i = blockIdx.x * blockDim.x + threadIdx.x;
  if (i < n) { a[i] = 0; b[i] = 0; }
}

// ---------------- BN/bias fold for BOTH layers in one launch -------------------
__global__ void bnprep2_kernel(const float* __restrict__ b1, const float* __restrict__ b2,
    const float* __restrict__ g, const float* __restrict__ bb,
    const float* __restrict__ rm, const float* __restrict__ rv,
    float* __restrict__ s1, float* __restrict__ h1, float* __restrict__ s2,
    float* __restrict__ h2) {
  int t = threadIdx.x;  // 256
  int c = t & 127;
  float s = g[c] / sqrtf(rv[c] + BN_EPS);
  const float* bias = (t < 128) ? b1 : b2;
  float* so = (t < 128) ? s1 : s2;
  float* ho = (t < 128) ? h1 : h2;
  so[c] = s;
  ho[c] = (bias[c] - rm[c]) * s + bb[c];
}

// ---------------- CSR build ----------------
__global__ void hist_kernel(const int* __restrict__ dst, int ne, int* __restrict__ deg) {
  int i = blockIdx.x * blockDim.x + threadIdx.x;
  int stride = gridDim.x * blockDim.x;
  for (; i < ne; i += stride) atomicAdd(&deg[dst[i]], 1);
}

__global__ __launch_bounds__(1024) void scan_kernel(const int* __restrict__ deg,
    int* __restrict__ offs, int n) {
  __shared__ int part[1024];
  int t = threadIdx.x;
  int chunk = (n + 1023) >> 10;
  int s0 = t * chunk;
  int s1 = min(n, s0 + chunk);
  int sum = 0;
  for (int i = s0; i < s1; ++i) sum += deg[i];
  part[t] = sum;
  __syncthreads();
  for (int off = 1; off < 1024; off <<= 1) {
    int v = (t >= off) ? part[t - off] : 0;
    __syncthreads();
    part[t] += v;
    __syncthreads();
  }
  int run = (t > 0) ? part[t - 1] : 0;
  for (int i = s0; i < s1; ++i) { offs[i] = run; run += deg[i]; }
}

__global__ void scatter_kernel(const int* __restrict__ src, const int* __restrict__ dst,
    int ne, const int* __restrict__ offs, int* __restrict__ cursor,
    int* __restrict__ csr_src) {
  int i = blockIdx.x * blockDim.x + threadIdx.x;
  int stride = gridDim.x * blockDim.x;
  for (; i < ne; i += stride) {
    int d = dst[i];
    int pos = offs[d] + atomicAdd(&cursor[d], 1);
    csr_src[pos] = src[i];
  }
}

// ---------------- GEMM: C[n,128] = A[n,128] @ W[128,128] (fp32) ----------------
// BOTH operands in LDS: W 64 KB + A-tile (32 rows) 16 KB = 80 KB -> 2 blocks/CU.
// Staging is coalesced streaming; the k-loop reads only LDS, so the previous
// design's per-k-iter global-latency chain (broadcast A loads, ~900cyc, ~90us)
// is gone. Block = 256 thr; thread = 4 rows x 4 cols (16 acc). One tile/block.
__global__ __launch_bounds__(256) void gemm128(const float* __restrict__ A,
    const float* __restrict__ W, float* __restrict__ C, int n) {
  __shared__ float Wl[128 * 128];  // 64 KB
  __shared__ float As[32 * 128];   // 16 KB
  int t = threadIdx.x;
  {
    const float4* Wv = (const float4*)W;
    float4* Wlv = (float4*)Wl;
#pragma unroll
    for (int i = 0; i < 16; ++i) Wlv[t + 256 * i] = Wv[t + 256 * i];
  }
  int r0 = blockIdx.x << 5;
  {
    float4* Asv = (float4*)As;
    if (r0 + 32 <= n) {
      const float4* Av = (const float4*)(A + (size_t)r0 * 128);
#pragma unroll
      for (int i = 0; i < 4; ++i) Asv[t + 256 * i] = Av[t + 256 * i];
    } else {
#pragma unroll
      for (int i = 0; i < 4; ++i) {
        int idx = t + 256 * i;
        int rr = idx >> 5;       // 32 float4 per row
        int cc = idx & 31;
        int gr = min(r0 + rr, n - 1);
        Asv[idx] = ((const float4*)(A + (size_t)gr * 128))[cc];
      }
    }
  }
  __syncthreads();
  int cg = t & 31;   // cols 4*cg .. 4*cg+3
  int rg = t >> 5;   // rows rg*4 .. rg*4+3 within tile
  float4 acc[4];
#pragma unroll
  for (int r = 0; r < 4; ++r) acc[r] = make_float4(0.f, 0.f, 0.f, 0.f);
#pragma unroll 4
  for (int k = 0; k < 128; k += 4) {
    float4 w0 = *(const float4*)&Wl[(k + 0) * 128 + cg * 4];
    float4 w1 = *(const float4*)&Wl[(k + 1) * 128 + cg * 4];
    float4 w2 = *(const float4*)&Wl[(k + 2) * 128 + cg * 4];
    float4 w3 = *(const float4*)&Wl[(k + 3) * 128 + cg * 4];
#pragma unroll
    for (int r = 0; r < 4; ++r) {
      float4 av = *(const float4*)&As[(rg * 4 + r) * 128 + k];
      acc[r].x += av.x * w0.x + av.y * w1.x + av.z * w2.x + av.w * w3.x;
      acc[r].y += av.x * w0.y + av.y * w1.y + av.z * w2.y + av.w * w3.y;
      acc[r].z += av.x * w0.z + av.y * w1.z + av.z * w2.z + av.w * w3.z;
      acc[r].w += av.x * w0.w + av.y * w1.w + av.z * w2.w + av.w * w3.w;
    }
  }
#pragma unroll
  for (int r = 0; r < 4; ++r) {
    int gr = r0 + rg * 4 + r;
    if (gr < n) *(float4*)&C[(size_t)gr * 128 + cg * 4] = acc[r];
  }
}

// ---------------- gate: gate[n] = tanh(h2 @ Wg1 + bg1) . Wg2 -------------------
// Same LDS-staged skeleton; epilogue: tanh + dot(Wg2) + 32-lane shfl reduce.
__global__ __launch_bounds__(256) void gate_kernel(const float* __restrict__ A,
    const float* __restrict__ Wg1, const float* __restrict__ bg1,
    const float* __restrict__ Wg2, float* __restrict__ gate, int n) {
  __shared__ float Wl[128 * 128];  // 64 KB
  __shared__ float As[32 * 128];   // 16 KB
  int t = threadIdx.x;
  {
    const float4* Wv = (const float4*)Wg1;
    float4* Wlv = (float4*)Wl;
#pragma unroll
    for (int i = 0; i < 16; ++i) Wlv[t + 256 * i] = Wv[t + 256 * i];
  }
  int r0 = blockIdx.x << 5;
  {
    float4* Asv = (float4*)As;
    if (r0 + 32 <= n) {
      const float4* Av = (const float4*)(A + (size_t)r0 * 128);
#pragma unroll
      for (int i = 0; i < 4; ++i) Asv[t + 256 * i] = Av[t + 256 * i];
    } else {
#pragma unroll
      for (int i = 0; i < 4; ++i) {
        int idx = t + 256 * i;
        int rr = idx >> 5;
        int cc = idx & 31;
        int gr = min(r0 + rr, n - 1);
        Asv[idx] = ((const float4*)(A + (size_t)gr * 128))[cc];
      }
    }
  }
  __syncthreads();
  int cg = t & 31;
  int rg = t >> 5;
  float4 bg4 = *(const float4*)&bg1[cg * 4];
  float4 wg4 = *(const float4*)&Wg2[cg * 4];
  float4 acc[4];
#pragma unroll
  for (int r = 0; r < 4; ++r) acc[r] = make_float4(0.f, 0.f, 0.f, 0.f);
#pragma unroll 4
  for (int k = 0; k < 128; k += 4) {
    float4 w0 = *(const float4*)&Wl[(k + 0) * 128 + cg * 4];
    float4 w1 = *(const float4*)&Wl[(k + 1) * 128 + cg * 4];
    float4 w2 = *(const float4*)&Wl[(k + 2) * 128 + cg * 4];
    float4 w3 = *(const float4*)&Wl[(k + 3) * 128 + cg * 4];
#pragma unroll
    for (int r = 0; r < 4; ++r) {
      float4 av = *(const float4*)&As[(rg * 4 + r) * 128 + k];
      acc[r].x += av.x * w0.x + av.y * w1.x + av.z * w2.x + av.w * w3.x;
      acc[r].y += av.x * w0.y + av.y * w1.y + av.z * w2.y + av.w * w3.y;
      acc[r].z += av.x * w0.z + av.y * w1.z + av.z * w2.z + av.w * w3.z;
      acc[r].w += av.x * w0.w + av.y * w1.w + av.z * w2.w + av.w * w3.w;
    }
  }
#pragma unroll
  for (int r = 0; r < 4; ++r) {
    float v = tanhf(acc[r].x + bg4.x) * wg4.x
            + tanhf(acc[r].y + bg4.y) * wg4.y
            + tanhf(acc[r].z + bg4.z) * wg4.z
            + tanhf(acc[r].w + bg4.w) * wg4.w;
    v += __shfl_xor(v, 1);
    v += __shfl_xor(v, 2);
    v += __shfl_xor(v, 4);
    v += __shfl_xor(v, 8);
    v += __shfl_xor(v, 16);
    int gr = r0 + rg * 4 + r;
    if (cg == 0 && gr < n) gate[gr] = v;
  }
}

// ---------------- GATv2 layer FUSED: one wave per node (proven 122us config) ---
// Exact R3-kernel config: block=64, grid=N, unroll x2, int32 indices. (R7's
// unroll x4 + uint16 regressed to 141us: compiler serialized load groups.)
// Lane = (edge-slot es = l>>3, chunk c = l&7); lane owns 16 channels c*16..+15.
// Layer 1 (REDUCE=false): chunk == head, score completes in-lane.
// Layer 2 (REDUCE=true): score = 128-dot, reduce over the 8 chunk lanes.
// No max-subtraction (scores O(1), softmax shift-invariant, exp safe).
template<bool REDUCE>
__global__ __launch_bounds__(64) void gat_fused(
    const float* __restrict__ xl, const float* __restrict__ xr,
    const int* __restrict__ csr_src, const int* __restrict__ offs,
    const int* __restrict__ deg, const float* __restrict__ att,
    const float* __restrict__ bnscale, const float* __restrict__ bnshift,
    float* __restrict__ out, int n_nodes) {
  int n = blockIdx.x;
  if (n >= n_nodes) return;
  int l = threadIdx.x;
  int c = l & 7;
  int es = l >> 3;
  int co = c * 16;

  float4 at4[4], xr4[4];
  {
    const float4* atp = (const float4*)(att + co);
    const float4* xrp = (const float4*)(xr + (size_t)n * 128 + co);
#pragma unroll
    for (int j = 0; j < 4; ++j) { at4[j] = atp[j]; xr4[j] = xrp[j]; }
  }
  int base = offs[n], d = deg[n];
  float acc[16];
#pragma unroll
  for (int j = 0; j < 16; ++j) acc[j] = 0.f;
  float ssum = 0.f;

  const int* cp = csr_src + base;
  int iters = (d + 7) >> 3;

  auto loadgrp = [&](int eidx, float4* v) -> bool {
    bool valid = eidx < d;
    int ecl = valid ? eidx : (d - 1);
    int sidx = cp[ecl];
    const float4* xp = (const float4*)(xl + (size_t)sidx * 128 + co);
#pragma unroll
    for (int j = 0; j < 4; ++j) v[j] = xp[j];
    return valid;
  };
  auto compute = [&](const float4* v, bool valid) {
    float p = 0.f;
#pragma unroll
    for (int j = 0; j < 4; ++j) {
      float t0 = v[j].x + xr4[j].x;
      float t1 = v[j].y + xr4[j].y;
      float t2 = v[j].z + xr4[j].z;
      float t3 = v[j].w + xr4[j].w;
      p += at4[j].x * (fmaxf(t0, 0.f) + NEG_SLOPE * fminf(t0, 0.f));
      p += at4[j].y * (fmaxf(t1, 0.f) + NEG_SLOPE * fminf(t1, 0.f));
      p += at4[j].z * (fmaxf(t2, 0.f) + NEG_SLOPE * fminf(t2, 0.f));
      p += at4[j].w * (fmaxf(t3, 0.f) + NEG_SLOPE * fminf(t3, 0.f));
    }
    if (REDUCE) {
      p += __shfl_xor(p, 1);
      p += __shfl_xor(p, 2);
      p += __shfl_xor(p, 4);
    }
    float ex = valid ? __expf(p) : 0.f;
    ssum += ex;
#pragma unroll
    for (int j = 0; j < 4; ++j) {
      acc[4 * j + 0] += ex * v[j].x;
      acc[4 * j + 1] += ex * v[j].y;
      acc[4 * j + 2] += ex * v[j].z;
      acc[4 * j + 3] += ex * v[j].w;
    }
  };

  int i = 0;
  for (; i + 2 <= iters; i += 2) {
    float4 v0[4], v1[4];
    bool a = loadgrp((i << 3) + es, v0);
    bool b = loadgrp(((i + 1) << 3) + es, v1);
    compute(v0, a);
    compute(v1, b);
  }
  if (i < iters) {
    float4 v0[4];
    bool a = loadgrp((i << 3) + es, v0);
    compute(v0, a);
  }

  // reduce across the 8 edge slots (once per node)
#pragma unroll
  for (int st = 8; st <= 32; st <<= 1) {
    ssum += __shfl_xor(ssum, st);
#pragma unroll
    for (int j = 0; j < 16; ++j) acc[j] += __shfl_xor(acc[j], st);
  }

  if (es == 0) {
    float inv = 1.f / (ssum + 1e-16f);
    const float4* scp = (const float4*)(bnscale + co);
    const float4* shp = (const float4*)(bnshift + co);
    float4* op = (float4*)(out + (size_t)n * 128 + co);
#pragma unroll
    for (int j = 0; j < 4; ++j) {
      float4 sc = scp[j], sh = shp[j];
      float4 o;
      o.x = fmaxf(acc[4 * j + 0] * inv * sc.x + sh.x, 0.f);
      o.y = fmaxf(acc[4 * j + 1] * inv * sc.y + sh.y, 0.f);
      o.z = fmaxf(acc[4 * j + 2] * inv * sc.z + sh.z, 0.f);
      o.w = fmaxf(acc[4 * j + 3] * inv * sc.w + sh.w, 0.f);
      op[j] = o;
    }
  }
}

// ---------------- pooling + fc head fused (one block per graph) ----------------
__global__ __launch_bounds__(128) void poolfc_kernel(const float* __restrict__ gate,
    const float* __restrict__ h2, const int* __restrict__ batch, int n_nodes,
    const float* __restrict__ Wf1, const float* __restrict__ bf1,
    const float* __restrict__ Wf2, const float* __restrict__ bf2,
    float* __restrict__ out, int n_graphs) {
  int g = blockIdx.x;
  if (g >= n_graphs) return;
  int t = threadIdx.x;
  int start = lower_bound_i(batch, n_nodes, g);
  int end = lower_bound_i(batch, n_nodes, g + 1);
  __shared__ float red[128];
  __shared__ float pl[128];
  float m = -__builtin_inff();
  for (int i = start + t; i < end; i += 128) m = fmaxf(m, gate[i]);
  red[t] = m;
  __syncthreads();
  for (int off = 64; off >= 1; off >>= 1) {
    if (t < off) red[t] = fmaxf(red[t], red[t + off]);
    __syncthreads();
  }
  m = red[0];
  __syncthreads();
  float s = 0.f, acc = 0.f;
  for (int i = start; i < end; ++i) {
    float ex = __expf(gate[i] - m);
    s += ex;
    acc += ex * h2[(size_t)i * 128 + t];
  }
  pl[t] = acc / (s + 1e-16f);
  __syncthreads();
  float v = 0.f;
  if (t < 100) {
    float a = bf1[t];
    for (int k = 0; k < 128; ++k) a += pl[k] * Wf1[k * 100 + t];
    v = fmaxf(a, 0.f) * Wf2[t];
  }
  red[t] = v;
  __syncthreads();
  for (int off = 64; off >= 1; off >>= 1) {
    if (t < off) red[t] += red[t + off];
    __syncthreads();
  }
  if (t == 0) out[g] = red[0] + bf2[0];
}

extern "C" void kernel_launch(void* const* d_in, const int* in_sizes, int n_in,
                              void* d_out, int out_size, void* d_ws, size_t ws_size,
                              hipStream_t stream) {
  const float* x     = (const float*)d_in[0];
  const int*   ei    = (const int*)d_in[1];
  const int*   batch = (const int*)d_in[2];
  const float* Wl1   = (const float*)d_in[3];
  const float* Wr1   = (const float*)d_in[4];
  const float* att1  = (const float*)d_in[5];
  const float* b1    = (const float*)d_in[6];
  const float* Wl2   = (const float*)d_in[7];
  const float* Wr2   = (const float*)d_in[8];
  const float* att2  = (const float*)d_in[9];
  const float* b2    = (const float*)d_in[10];
  const float* bn_g  = (const float*)d_in[11];
  const float* bn_b  = (const float*)d_in[12];
  const float* bn_rm = (const float*)d_in[13];
  const float* bn_rv = (const float*)d_in[14];
  const float* Wg1   = (const float*)d_in[15];
  const float* bg1   = (const float*)d_in[16];
  const float* Wg2   = (const float*)d_in[17];
  const float* Wf1   = (const float*)d_in[18];
  const float* bf1   = (const float*)d_in[19];
  const float* Wf2   = (const float*)d_in[20];
  const float* bf2   = (const float*)d_in[21];

  const int N  = in_sizes[0] / 128;
  const int E  = in_sizes[1] / 2;
  const int NG = out_size;
  const int* src = ei;
  const int* dst = ei + E;

  // ---- workspace arena (256B-aligned) ----
  char* p = (char*)d_ws;
  auto alloc = [&](size_t bytes) -> void* {
    void* r = (void*)p;
    p += (bytes + 255) & ~(size_t)255;
    return r;
  };
  float* bufA    = (float*)alloc((size_t)N * 128 * 4);  // xl1, later xl2
  float* bufB    = (float*)alloc((size_t)N * 128 * 4);  // xr1, later xr2
  float* h1      = (float*)alloc((size_t)N * 128 * 4);  // h1, later reused as h2
  int*   deg     = (int*)alloc((size_t)N * 4);
  int*   cursor  = (int*)alloc((size_t)N * 4);
  int*   offs    = (int*)alloc((size_t)N * 4);
  int*   csr_src = (int*)alloc((size_t)E * 4);
  float* gate    = (float*)alloc((size_t)N * 4);
  float* bns1    = (float*)alloc(128 * 4);
  float* bnh1    = (float*)alloc(128 * 4);
  float* bns2    = (float*)alloc(128 * 4);
  float* bnh2    = (float*)alloc(128 * 4);
  float* h2      = h1;  // h1 dead after layer-2 GEMMs; safe alias (in-order stream)

  const int gemm_grid = (N + 31) >> 5;   // one 32-row tile per block

  // ---- CSR build + BN prep ----
  zero2_kernel<<<(N + 255) / 256, 256, 0, stream>>>(deg, cursor, N);
  hist_kernel<<<1024, 256, 0, stream>>>(dst, E, deg);
  scan_kernel<<<1, 1024, 0, stream>>>(deg, offs, N);
  scatter_kernel<<<1024, 256, 0, stream>>>(src, dst, E, offs, cursor, csr_src);
  bnprep2_kernel<<<1, 256, 0, stream>>>(b1, b2, bn_g, bn_b, bn_rm, bn_rv,
                                        bns1, bnh1, bns2, bnh2);

  // ---- layer 1 ----
  gemm128<<<gemm_grid, 256, 0, stream>>>(x, Wl1, bufA, N);
  gemm128<<<gemm_grid, 256, 0, stream>>>(x, Wr1, bufB, N);
  gat_fused<false><<<N, 64, 0, stream>>>(bufA, bufB, csr_src, offs, deg, att1,
                                         bns1, bnh1, h1, N);

  // ---- layer 2 ----
  gemm128<<<gemm_grid, 256, 0, stream>>>(h1, Wl2, bufA, N);
  gemm128<<<gemm_grid, 256, 0, stream>>>(h1, Wr2, bufB, N);
  gat_fused<true><<<N, 64, 0, stream>>>(bufA, bufB, csr_src, offs, deg, att2,
                                        bns2, bnh2, h2, N);

  // ---- pooling + head ----
  gate_kernel<<<gemm_grid, 256, 0, stream>>>(h2, Wg1, bg1, Wg2, gate, N);
  poolfc_kernel<<<NG, 128, 0, stream>>>(gate, h2, batch, N, Wf1, bf1, Wf2, bf2,
                                        (float*)d_out, NG);
}